// Round 1
// baseline (8022.549 us; speedup 1.0000x reference)
//
#include <hip/hip_runtime.h>

#define NN 50000
#define NE 1600000
#define DIM 32
#define HS 0.1f

static inline int cdiv(int a, int b) { return (a + b - 1) / b; }

// ---------------- setup kernels ----------------

__global__ void k_zero_ints(int* __restrict__ p, int n) {
    int i = blockIdx.x * blockDim.x + threadIdx.x;
    if (i < n) p[i] = 0;
}

__global__ void k_hist(const int* __restrict__ dst, int* __restrict__ cnt) {
    int i = blockIdx.x * blockDim.x + threadIdx.x;
    if (i < NE) atomicAdd(&cnt[dst[i]], 1);
}

// per-chunk (1024) inclusive scan -> row_ptr[g+1], chunk totals -> partials[b]
__global__ __launch_bounds__(1024) void k_scanA(const int* __restrict__ cnt,
                                                int* __restrict__ row_ptr,
                                                int* __restrict__ partials) {
    __shared__ int s[1024];
    int t = threadIdx.x;
    int g = blockIdx.x * 1024 + t;
    int v = (g < NN) ? cnt[g] : 0;
    s[t] = v;
    __syncthreads();
    for (int off = 1; off < 1024; off <<= 1) {
        int add = (t >= off) ? s[t - off] : 0;
        __syncthreads();
        s[t] += add;
        __syncthreads();
    }
    if (g < NN) row_ptr[g + 1] = s[t];
    if (t == 1023) partials[blockIdx.x] = s[t];
}

__global__ void k_scanB(int* __restrict__ partials, int nb) {
    if (threadIdx.x == 0 && blockIdx.x == 0) {
        int run = 0;
        for (int i = 0; i < nb; i++) { int v = partials[i]; partials[i] = run; run += v; }
    }
}

__global__ void k_scanC(int* __restrict__ row_ptr, const int* __restrict__ partials) {
    int g = blockIdx.x * blockDim.x + threadIdx.x;
    if (g < NN) row_ptr[g + 1] += partials[g >> 10];
    if (g == 0) row_ptr[0] = 0;
}

__global__ void k_dis(const int* __restrict__ row_ptr, float* __restrict__ dis) {
    int n = blockIdx.x * blockDim.x + threadIdx.x;
    if (n < NN) {
        int deg = row_ptr[n + 1] - row_ptr[n];
        dis[n] = rsqrtf((float)deg + 1.0f);  // +1 self-loop
    }
}

// scatter edges into CSR slots; record {src, dis[src]*dis[dst]} as float2
__global__ void k_fill(const int* __restrict__ src, const int* __restrict__ dst,
                       const int* __restrict__ row_ptr, const float* __restrict__ dis,
                       int* __restrict__ fill, float2* __restrict__ cw) {
    int i = blockIdx.x * blockDim.x + threadIdx.x;
    if (i < NE) {
        int s = src[i], d = dst[i];
        int slot = row_ptr[d] + atomicAdd(&fill[d], 1);
        cw[slot] = make_float2(__int_as_float(s), dis[s] * dis[d]);
    }
}

// ---------------- main-loop kernels ----------------

// xw = rowwise (src [+ coef*acc]) @ W ; optional writeback of the updated row to copy_out
// 32 rows per block, 256 threads; x tile padded to stride 33 (kills 8-way LDS conflict)
__global__ __launch_bounds__(256) void k_matmul(const float* __restrict__ src,
                                                const float* __restrict__ W,
                                                float* __restrict__ xw,
                                                float* __restrict__ copy_out,
                                                const float* __restrict__ acc,
                                                float coef) {
    __shared__ float sW[DIM * DIM];
    __shared__ float sX[32 * 33];
    int t = threadIdx.x;
#pragma unroll
    for (int k = 0; k < 4; k++) { int i = k * 256 + t; sW[i] = W[i]; }
    size_t base = (size_t)blockIdx.x * 32 * DIM;
#pragma unroll
    for (int k = 0; k < 4; k++) {
        int i = k * 256 + t;  // 0..1023, coalesced
        size_t g = base + i;
        float v = 0.f;
        if (g < (size_t)NN * DIM) {
            v = src[g];
            if (acc) v = fmaf(coef, acc[g], v);
            if (copy_out) copy_out[g] = v;
        }
        sX[(i >> 5) * 33 + (i & 31)] = v;
    }
    __syncthreads();
    int r = t >> 3, oct = t & 7;
    int row = blockIdx.x * 32 + r;
    if (row >= NN) return;
    float a0 = 0.f, a1 = 0.f, a2 = 0.f, a3 = 0.f;
    const float* xr = &sX[r * 33];
#pragma unroll
    for (int i = 0; i < DIM; i++) {
        float xv = xr[i];
        const float* wr = &sW[i * DIM + oct * 4];
        a0 = fmaf(xv, wr[0], a0);
        a1 = fmaf(xv, wr[1], a1);
        a2 = fmaf(xv, wr[2], a2);
        a3 = fmaf(xv, wr[3], a3);
    }
    float4 o = make_float4(a0, a1, a2, a3);
    *(float4*)&xw[(size_t)row * DIM + oct * 4] = o;
}

// pull-aggregate + RK4 epilogue.
// k = relu(sum_e w_e*xw[src_e] + dn*dn*xw[n] + b) * sigmoid(t*wt)
// acc = acc_init ? c*k : acc + c*k
// stage_out = x_cur + stage_coef*k   (if stage_coef != 0)
// final_out = x_cur + (h/6)*acc      (last stage of last step)
__global__ __launch_bounds__(256) void k_agg(const int* __restrict__ row_ptr,
                                             const float2* __restrict__ cw,
                                             const float* __restrict__ dis,
                                             const float* __restrict__ xw,
                                             const float* __restrict__ b,
                                             const float* __restrict__ wt, float t,
                                             const float* __restrict__ x_cur,
                                             float* __restrict__ acc,
                                             int acc_init, float acc_coef,
                                             float* __restrict__ stage_out, float stage_coef,
                                             float* __restrict__ final_out) {
    int tid = threadIdx.x;
    int j = tid & 31;               // column
    int n = blockIdx.x * 8 + (tid >> 5);  // 8 nodes per block
    if (n >= NN) return;
    int e0 = row_ptr[n], e1 = row_ptr[n + 1];
    float sum = 0.f;
    for (int e = e0; e < e1; ++e) {
        float2 p = cw[e];                 // 8B broadcast across the 32-lane group
        int s = __float_as_int(p.x);
        sum = fmaf(p.y, xw[(size_t)s * DIM + j], sum);  // coalesced 128B row
    }
    float dn = dis[n];
    sum = fmaf(dn * dn, xw[(size_t)n * DIM + j], sum) + b[j];
    float kv = fmaxf(sum, 0.f);
    kv *= 1.f / (1.f + __expf(-t * wt[j]));
    size_t o = (size_t)n * DIM + j;
    float a = acc_init ? (acc_coef * kv) : fmaf(acc_coef, kv, acc[o]);
    if (final_out) {
        final_out[o] = fmaf(HS / 6.f, a, x_cur[o]);
    } else {
        acc[o] = a;
        if (stage_coef != 0.f) stage_out[o] = fmaf(stage_coef, kv, x_cur[o]);
    }
}

// ---------------- host ----------------

extern "C" void kernel_launch(void* const* d_in, const int* in_sizes, int n_in,
                              void* d_out, int out_size, void* d_ws, size_t ws_size,
                              hipStream_t stream) {
    const float* x   = (const float*)d_in[0];
    const int* epos  = (const int*)d_in[1];
    const int* eneg  = (const int*)d_in[2];
    const float* Wp  = (const float*)d_in[3];
    const float* bp  = (const float*)d_in[4];
    const float* wtp = (const float*)d_in[5];
    const float* Wn  = (const float*)d_in[6];
    const float* bn  = (const float*)d_in[7];
    const float* wtn = (const float*)d_in[8];
    float* out = (float*)d_out;

    char* ws = (char*)d_ws;
    size_t off = 0;
    auto alloc = [&](size_t bytes) -> void* {
        void* p = ws + off;
        off += (bytes + 255) & ~(size_t)255;
        return p;
    };

    struct Sign {
        int *row_ptr, *cnt, *fill, *partials;
        float* dis;
        float2* cw;
        float *x_cur, *xw, *acc, *stage;
        const int *src, *dst;
        const float *W, *b, *wt;
        float* zout;
    } S[2];

    for (int s = 0; s < 2; s++) {
        S[s].row_ptr  = (int*)alloc((NN + 1) * sizeof(int));
        int* cntfill  = (int*)alloc((size_t)2 * NN * sizeof(int));
        S[s].cnt = cntfill;
        S[s].fill = cntfill + NN;
        S[s].partials = (int*)alloc(256);
        S[s].dis      = (float*)alloc(NN * sizeof(float));
        S[s].cw       = (float2*)alloc((size_t)NE * sizeof(float2));
        S[s].x_cur    = (float*)alloc((size_t)NN * DIM * sizeof(float));
        S[s].xw       = (float*)alloc((size_t)NN * DIM * sizeof(float));
        S[s].acc      = (float*)alloc((size_t)NN * DIM * sizeof(float));
        S[s].stage    = (float*)alloc((size_t)NN * DIM * sizeof(float));
    }
    S[0].src = epos; S[0].dst = epos + NE; S[0].W = Wp; S[0].b = bp; S[0].wt = wtp;
    S[0].zout = out;
    S[1].src = eneg; S[1].dst = eneg + NE; S[1].W = Wn; S[1].b = bn; S[1].wt = wtn;
    S[1].zout = out + (size_t)NN * DIM;

    const int nbScan = cdiv(NN, 1024);

    // ---- setup: build CSR + norms for both signs ----
    for (int s = 0; s < 2; s++) {
        k_zero_ints<<<cdiv(2 * NN, 256), 256, 0, stream>>>(S[s].cnt, 2 * NN);
        k_hist<<<cdiv(NE, 256), 256, 0, stream>>>(S[s].dst, S[s].cnt);
        k_scanA<<<nbScan, 1024, 0, stream>>>(S[s].cnt, S[s].row_ptr, S[s].partials);
        k_scanB<<<1, 1, 0, stream>>>(S[s].partials, nbScan);
        k_scanC<<<cdiv(NN, 256), 256, 0, stream>>>(S[s].row_ptr, S[s].partials);
        k_dis<<<cdiv(NN, 256), 256, 0, stream>>>(S[s].row_ptr, S[s].dis);
        k_fill<<<cdiv(NE, 256), 256, 0, stream>>>(S[s].src, S[s].dst, S[s].row_ptr,
                                                  S[s].dis, S[s].fill, S[s].cw);
    }

    const int mmGrid = cdiv(NN, 32);   // 1563
    const int agGrid = cdiv(NN, 8);    // 6250

    // ---- RK4 main loop ----
    for (int s = 0; s < 2; s++) {
        for (int st = 0; st < 10; st++) {
            float tb = HS * (float)st;
            // B1: (x update fused) + matmul
            if (st == 0)
                k_matmul<<<mmGrid, 256, 0, stream>>>(x, S[s].W, S[s].xw, S[s].x_cur,
                                                     (const float*)nullptr, 0.f);
            else
                k_matmul<<<mmGrid, 256, 0, stream>>>(S[s].x_cur, S[s].W, S[s].xw, S[s].x_cur,
                                                     S[s].acc, HS / 6.f);
            // A1: k1 ; acc=k1 ; stage = x + h/2 k1
            k_agg<<<agGrid, 256, 0, stream>>>(S[s].row_ptr, S[s].cw, S[s].dis, S[s].xw,
                                              S[s].b, S[s].wt, tb, S[s].x_cur, S[s].acc,
                                              1, 1.f, S[s].stage, HS * 0.5f, (float*)nullptr);
            // B2
            k_matmul<<<mmGrid, 256, 0, stream>>>(S[s].stage, S[s].W, S[s].xw,
                                                 (float*)nullptr, (const float*)nullptr, 0.f);
            // A2: acc += 2k2 ; stage = x + h/2 k2
            k_agg<<<agGrid, 256, 0, stream>>>(S[s].row_ptr, S[s].cw, S[s].dis, S[s].xw,
                                              S[s].b, S[s].wt, tb + HS * 0.5f, S[s].x_cur, S[s].acc,
                                              0, 2.f, S[s].stage, HS * 0.5f, (float*)nullptr);
            // B3
            k_matmul<<<mmGrid, 256, 0, stream>>>(S[s].stage, S[s].W, S[s].xw,
                                                 (float*)nullptr, (const float*)nullptr, 0.f);
            // A3: acc += 2k3 ; stage = x + h k3
            k_agg<<<agGrid, 256, 0, stream>>>(S[s].row_ptr, S[s].cw, S[s].dis, S[s].xw,
                                              S[s].b, S[s].wt, tb + HS * 0.5f, S[s].x_cur, S[s].acc,
                                              0, 2.f, S[s].stage, HS, (float*)nullptr);
            // B4
            k_matmul<<<mmGrid, 256, 0, stream>>>(S[s].stage, S[s].W, S[s].xw,
                                                 (float*)nullptr, (const float*)nullptr, 0.f);
            // A4: acc += k4 ; if last step -> z = x + h/6 acc to d_out
            bool last = (st == 9);
            k_agg<<<agGrid, 256, 0, stream>>>(S[s].row_ptr, S[s].cw, S[s].dis, S[s].xw,
                                              S[s].b, S[s].wt, tb + HS, S[s].x_cur, S[s].acc,
                                              0, 1.f, S[s].stage, 0.f,
                                              last ? S[s].zout : (float*)nullptr);
        }
    }
}

// Round 2
// 3409.481 us; speedup vs baseline: 2.3530x; 2.3530x over previous
//
#include <hip/hip_runtime.h>

#define NN 50000
#define NE 1600000
#define DIM 32
#define HS 0.1f

static inline int cdiv(int a, int b) { return (a + b - 1) / b; }

// ---------------- setup kernels ----------------

__global__ void k_zero_ints(int* __restrict__ p, int n) {
    int i = blockIdx.x * blockDim.x + threadIdx.x;
    if (i < n) p[i] = 0;
}

__global__ void k_hist(const int* __restrict__ dst, int* __restrict__ cnt) {
    int i = blockIdx.x * blockDim.x + threadIdx.x;
    if (i < NE) atomicAdd(&cnt[dst[i]], 1);
}

// per-chunk (1024) inclusive scan -> row_ptr[g+1], chunk totals -> partials[b]
__global__ __launch_bounds__(1024) void k_scanA(const int* __restrict__ cnt,
                                                int* __restrict__ row_ptr,
                                                int* __restrict__ partials) {
    __shared__ int s[1024];
    int t = threadIdx.x;
    int g = blockIdx.x * 1024 + t;
    int v = (g < NN) ? cnt[g] : 0;
    s[t] = v;
    __syncthreads();
    for (int off = 1; off < 1024; off <<= 1) {
        int add = (t >= off) ? s[t - off] : 0;
        __syncthreads();
        s[t] += add;
        __syncthreads();
    }
    if (g < NN) row_ptr[g + 1] = s[t];
    if (t == 1023) partials[blockIdx.x] = s[t];
}

__global__ void k_scanB(int* __restrict__ partials, int nb) {
    if (threadIdx.x == 0 && blockIdx.x == 0) {
        int run = 0;
        for (int i = 0; i < nb; i++) { int v = partials[i]; partials[i] = run; run += v; }
    }
}

__global__ void k_scanC(int* __restrict__ row_ptr, const int* __restrict__ partials) {
    int g = blockIdx.x * blockDim.x + threadIdx.x;
    if (g < NN) row_ptr[g + 1] += partials[g >> 10];
    if (g == 0) row_ptr[0] = 0;
}

__global__ void k_dis(const int* __restrict__ row_ptr, float* __restrict__ dis) {
    int n = blockIdx.x * blockDim.x + threadIdx.x;
    if (n < NN) {
        int deg = row_ptr[n + 1] - row_ptr[n];
        dis[n] = rsqrtf((float)deg + 1.0f);  // +1 self-loop
    }
}

// scatter edges into CSR slots; record {src, dis[src]*dis[dst]} as float2
__global__ void k_fill(const int* __restrict__ src, const int* __restrict__ dst,
                       const int* __restrict__ row_ptr, const float* __restrict__ dis,
                       int* __restrict__ fill, float2* __restrict__ cw) {
    int i = blockIdx.x * blockDim.x + threadIdx.x;
    if (i < NE) {
        int s = src[i], d = dst[i];
        int slot = row_ptr[d] + atomicAdd(&fill[d], 1);
        cw[slot] = make_float2(__int_as_float(s), dis[s] * dis[d]);
    }
}

// ---------------- main-loop kernels ----------------

// xw = rowwise (src [+ coef*acc]) @ W ; optional writeback of the updated row to copy_out
// 32 rows per block, 256 threads; x tile padded to stride 33 (kills 8-way LDS conflict)
__global__ __launch_bounds__(256) void k_matmul(const float* __restrict__ src,
                                                const float* __restrict__ W,
                                                float* __restrict__ xw,
                                                float* __restrict__ copy_out,
                                                const float* __restrict__ acc,
                                                float coef) {
    __shared__ float sW[DIM * DIM];
    __shared__ float sX[32 * 33];
    int t = threadIdx.x;
#pragma unroll
    for (int k = 0; k < 4; k++) { int i = k * 256 + t; sW[i] = W[i]; }
    size_t base = (size_t)blockIdx.x * 32 * DIM;
#pragma unroll
    for (int k = 0; k < 4; k++) {
        int i = k * 256 + t;  // 0..1023, coalesced
        size_t g = base + i;
        float v = 0.f;
        if (g < (size_t)NN * DIM) {
            v = src[g];
            if (acc) v = fmaf(coef, acc[g], v);
            if (copy_out) copy_out[g] = v;
        }
        sX[(i >> 5) * 33 + (i & 31)] = v;
    }
    __syncthreads();
    int r = t >> 3, oct = t & 7;
    int row = blockIdx.x * 32 + r;
    if (row >= NN) return;
    float a0 = 0.f, a1 = 0.f, a2 = 0.f, a3 = 0.f;
    const float* xr = &sX[r * 33];
#pragma unroll
    for (int i = 0; i < DIM; i++) {
        float xv = xr[i];
        const float* wr = &sW[i * DIM + oct * 4];
        a0 = fmaf(xv, wr[0], a0);
        a1 = fmaf(xv, wr[1], a1);
        a2 = fmaf(xv, wr[2], a2);
        a3 = fmaf(xv, wr[3], a3);
    }
    float4 o = make_float4(a0, a1, a2, a3);
    *(float4*)&xw[(size_t)row * DIM + oct * 4] = o;
}

// pull-aggregate + RK4 epilogue.  8 lanes per node, float4 per lane (4 cols).
// k = relu(sum_e w_e*xw[src_e] + dn*dn*xw[n] + b) * sigmoid(t*wt)
// acc = acc_init ? c*k : acc + c*k
// stage_out = x_cur + stage_coef*k   (if stage_coef != 0)
// final_out = x_cur + (h/6)*acc      (last stage of last step)
__global__ __launch_bounds__(256) void k_agg(const int* __restrict__ row_ptr,
                                             const float2* __restrict__ cw,
                                             const float* __restrict__ dis,
                                             const float* __restrict__ xw,
                                             const float* __restrict__ b,
                                             const float* __restrict__ wt, float t,
                                             const float* __restrict__ x_cur,
                                             float* __restrict__ acc,
                                             int acc_init, float acc_coef,
                                             float* __restrict__ stage_out, float stage_coef,
                                             float* __restrict__ final_out) {
    int tid = threadIdx.x;
    int q = tid & 7;                        // quad index: columns q*4 .. q*4+3
    int n = blockIdx.x * 32 + (tid >> 3);   // 32 nodes per 256-thread block
    if (n >= NN) return;
    int e0 = row_ptr[n], e1 = row_ptr[n + 1];
    const float* xwq = xw + q * 4;
    float4 sum = make_float4(0.f, 0.f, 0.f, 0.f);
    int e = e0;
    // unroll 4: 4 independent cw loads + 4 independent 16B gathers in flight
    for (; e + 3 < e1; e += 4) {
        float2 p0 = cw[e];
        float2 p1 = cw[e + 1];
        float2 p2 = cw[e + 2];
        float2 p3 = cw[e + 3];
        float4 v0 = *(const float4*)&xwq[(size_t)__float_as_int(p0.x) * DIM];
        float4 v1 = *(const float4*)&xwq[(size_t)__float_as_int(p1.x) * DIM];
        float4 v2 = *(const float4*)&xwq[(size_t)__float_as_int(p2.x) * DIM];
        float4 v3 = *(const float4*)&xwq[(size_t)__float_as_int(p3.x) * DIM];
        sum.x = fmaf(p0.y, v0.x, sum.x); sum.y = fmaf(p0.y, v0.y, sum.y);
        sum.z = fmaf(p0.y, v0.z, sum.z); sum.w = fmaf(p0.y, v0.w, sum.w);
        sum.x = fmaf(p1.y, v1.x, sum.x); sum.y = fmaf(p1.y, v1.y, sum.y);
        sum.z = fmaf(p1.y, v1.z, sum.z); sum.w = fmaf(p1.y, v1.w, sum.w);
        sum.x = fmaf(p2.y, v2.x, sum.x); sum.y = fmaf(p2.y, v2.y, sum.y);
        sum.z = fmaf(p2.y, v2.z, sum.z); sum.w = fmaf(p2.y, v2.w, sum.w);
        sum.x = fmaf(p3.y, v3.x, sum.x); sum.y = fmaf(p3.y, v3.y, sum.y);
        sum.z = fmaf(p3.y, v3.z, sum.z); sum.w = fmaf(p3.y, v3.w, sum.w);
    }
    for (; e < e1; ++e) {
        float2 p = cw[e];
        float4 v = *(const float4*)&xwq[(size_t)__float_as_int(p.x) * DIM];
        sum.x = fmaf(p.y, v.x, sum.x); sum.y = fmaf(p.y, v.y, sum.y);
        sum.z = fmaf(p.y, v.z, sum.z); sum.w = fmaf(p.y, v.w, sum.w);
    }
    float dn = dis[n];
    float sn = dn * dn;
    float4 vn = *(const float4*)&xwq[(size_t)n * DIM];
    float4 bb = *(const float4*)&b[q * 4];
    sum.x = fmaf(sn, vn.x, sum.x) + bb.x;
    sum.y = fmaf(sn, vn.y, sum.y) + bb.y;
    sum.z = fmaf(sn, vn.z, sum.z) + bb.z;
    sum.w = fmaf(sn, vn.w, sum.w) + bb.w;
    float4 w4 = *(const float4*)&wt[q * 4];
    float4 kv;
    kv.x = fmaxf(sum.x, 0.f) / (1.f + __expf(-t * w4.x));
    kv.y = fmaxf(sum.y, 0.f) / (1.f + __expf(-t * w4.y));
    kv.z = fmaxf(sum.z, 0.f) / (1.f + __expf(-t * w4.z));
    kv.w = fmaxf(sum.w, 0.f) / (1.f + __expf(-t * w4.w));
    size_t o = (size_t)n * DIM + q * 4;
    float4 a;
    if (acc_init) {
        a.x = acc_coef * kv.x; a.y = acc_coef * kv.y;
        a.z = acc_coef * kv.z; a.w = acc_coef * kv.w;
    } else {
        float4 ap = *(const float4*)&acc[o];
        a.x = fmaf(acc_coef, kv.x, ap.x); a.y = fmaf(acc_coef, kv.y, ap.y);
        a.z = fmaf(acc_coef, kv.z, ap.z); a.w = fmaf(acc_coef, kv.w, ap.w);
    }
    float4 xc = *(const float4*)&x_cur[o];
    if (final_out) {
        float4 z;
        z.x = fmaf(HS / 6.f, a.x, xc.x); z.y = fmaf(HS / 6.f, a.y, xc.y);
        z.z = fmaf(HS / 6.f, a.z, xc.z); z.w = fmaf(HS / 6.f, a.w, xc.w);
        *(float4*)&final_out[o] = z;
    } else {
        *(float4*)&acc[o] = a;
        if (stage_coef != 0.f) {
            float4 sg;
            sg.x = fmaf(stage_coef, kv.x, xc.x); sg.y = fmaf(stage_coef, kv.y, xc.y);
            sg.z = fmaf(stage_coef, kv.z, xc.z); sg.w = fmaf(stage_coef, kv.w, xc.w);
            *(float4*)&stage_out[o] = sg;
        }
    }
}

// ---------------- host ----------------

extern "C" void kernel_launch(void* const* d_in, const int* in_sizes, int n_in,
                              void* d_out, int out_size, void* d_ws, size_t ws_size,
                              hipStream_t stream) {
    const float* x   = (const float*)d_in[0];
    const int* epos  = (const int*)d_in[1];
    const int* eneg  = (const int*)d_in[2];
    const float* Wp  = (const float*)d_in[3];
    const float* bp  = (const float*)d_in[4];
    const float* wtp = (const float*)d_in[5];
    const float* Wn  = (const float*)d_in[6];
    const float* bn  = (const float*)d_in[7];
    const float* wtn = (const float*)d_in[8];
    float* out = (float*)d_out;

    char* ws = (char*)d_ws;
    size_t off = 0;
    auto alloc = [&](size_t bytes) -> void* {
        void* p = ws + off;
        off += (bytes + 255) & ~(size_t)255;
        return p;
    };

    struct Sign {
        int *row_ptr, *cnt, *fill, *partials;
        float* dis;
        float2* cw;
        float *x_cur, *xw, *acc, *stage;
        const int *src, *dst;
        const float *W, *b, *wt;
        float* zout;
    } S[2];

    for (int s = 0; s < 2; s++) {
        S[s].row_ptr  = (int*)alloc((NN + 1) * sizeof(int));
        int* cntfill  = (int*)alloc((size_t)2 * NN * sizeof(int));
        S[s].cnt = cntfill;
        S[s].fill = cntfill + NN;
        S[s].partials = (int*)alloc(256);
        S[s].dis      = (float*)alloc(NN * sizeof(float));
        S[s].cw       = (float2*)alloc((size_t)NE * sizeof(float2));
        S[s].x_cur    = (float*)alloc((size_t)NN * DIM * sizeof(float));
        S[s].xw       = (float*)alloc((size_t)NN * DIM * sizeof(float));
        S[s].acc      = (float*)alloc((size_t)NN * DIM * sizeof(float));
        S[s].stage    = (float*)alloc((size_t)NN * DIM * sizeof(float));
    }
    S[0].src = epos; S[0].dst = epos + NE; S[0].W = Wp; S[0].b = bp; S[0].wt = wtp;
    S[0].zout = out;
    S[1].src = eneg; S[1].dst = eneg + NE; S[1].W = Wn; S[1].b = bn; S[1].wt = wtn;
    S[1].zout = out + (size_t)NN * DIM;

    const int nbScan = cdiv(NN, 1024);

    // ---- setup: build CSR + norms for both signs ----
    for (int s = 0; s < 2; s++) {
        k_zero_ints<<<cdiv(2 * NN, 256), 256, 0, stream>>>(S[s].cnt, 2 * NN);
        k_hist<<<cdiv(NE, 256), 256, 0, stream>>>(S[s].dst, S[s].cnt);
        k_scanA<<<nbScan, 1024, 0, stream>>>(S[s].cnt, S[s].row_ptr, S[s].partials);
        k_scanB<<<1, 1, 0, stream>>>(S[s].partials, nbScan);
        k_scanC<<<cdiv(NN, 256), 256, 0, stream>>>(S[s].row_ptr, S[s].partials);
        k_dis<<<cdiv(NN, 256), 256, 0, stream>>>(S[s].row_ptr, S[s].dis);
        k_fill<<<cdiv(NE, 256), 256, 0, stream>>>(S[s].src, S[s].dst, S[s].row_ptr,
                                                  S[s].dis, S[s].fill, S[s].cw);
    }

    const int mmGrid = cdiv(NN, 32);   // 1563
    const int agGrid = cdiv(NN, 32);   // 1563 (32 nodes per 256-thread block)

    // ---- RK4 main loop ----
    for (int s = 0; s < 2; s++) {
        for (int st = 0; st < 10; st++) {
            float tb = HS * (float)st;
            // B1: (x update fused) + matmul
            if (st == 0)
                k_matmul<<<mmGrid, 256, 0, stream>>>(x, S[s].W, S[s].xw, S[s].x_cur,
                                                     (const float*)nullptr, 0.f);
            else
                k_matmul<<<mmGrid, 256, 0, stream>>>(S[s].x_cur, S[s].W, S[s].xw, S[s].x_cur,
                                                     S[s].acc, HS / 6.f);
            // A1: k1 ; acc=k1 ; stage = x + h/2 k1
            k_agg<<<agGrid, 256, 0, stream>>>(S[s].row_ptr, S[s].cw, S[s].dis, S[s].xw,
                                              S[s].b, S[s].wt, tb, S[s].x_cur, S[s].acc,
                                              1, 1.f, S[s].stage, HS * 0.5f, (float*)nullptr);
            // B2
            k_matmul<<<mmGrid, 256, 0, stream>>>(S[s].stage, S[s].W, S[s].xw,
                                                 (float*)nullptr, (const float*)nullptr, 0.f);
            // A2: acc += 2k2 ; stage = x + h/2 k2
            k_agg<<<agGrid, 256, 0, stream>>>(S[s].row_ptr, S[s].cw, S[s].dis, S[s].xw,
                                              S[s].b, S[s].wt, tb + HS * 0.5f, S[s].x_cur, S[s].acc,
                                              0, 2.f, S[s].stage, HS * 0.5f, (float*)nullptr);
            // B3
            k_matmul<<<mmGrid, 256, 0, stream>>>(S[s].stage, S[s].W, S[s].xw,
                                                 (float*)nullptr, (const float*)nullptr, 0.f);
            // A3: acc += 2k3 ; stage = x + h k3
            k_agg<<<agGrid, 256, 0, stream>>>(S[s].row_ptr, S[s].cw, S[s].dis, S[s].xw,
                                              S[s].b, S[s].wt, tb + HS * 0.5f, S[s].x_cur, S[s].acc,
                                              0, 2.f, S[s].stage, HS, (float*)nullptr);
            // B4
            k_matmul<<<mmGrid, 256, 0, stream>>>(S[s].stage, S[s].W, S[s].xw,
                                                 (float*)nullptr, (const float*)nullptr, 0.f);
            // A4: acc += k4 ; if last step -> z = x + h/6 acc to d_out
            bool last = (st == 9);
            k_agg<<<agGrid, 256, 0, stream>>>(S[s].row_ptr, S[s].cw, S[s].dis, S[s].xw,
                                              S[s].b, S[s].wt, tb + HS, S[s].x_cur, S[s].acc,
                                              0, 1.f, S[s].stage, 0.f,
                                              last ? S[s].zout : (float*)nullptr);
        }
    }
}

// Round 3
// 2535.508 us; speedup vs baseline: 3.1641x; 1.3447x over previous
//
#include <hip/hip_runtime.h>

#define NN 50000
#define NE 1600000
#define DIM 32
#define HS 0.1f
#define NBLK 1563   // cdiv(NN, 32)

static inline int cdiv(int a, int b) { return (a + b - 1) / b; }

// ---------------- setup kernels ----------------

__global__ void k_zero_ints(int* __restrict__ p, int n) {
    int i = blockIdx.x * blockDim.x + threadIdx.x;
    if (i < n) p[i] = 0;
}

__global__ void k_hist(const int* __restrict__ dst, int* __restrict__ cnt) {
    int i = blockIdx.x * blockDim.x + threadIdx.x;
    if (i < NE) atomicAdd(&cnt[dst[i]], 1);
}

// per-chunk (1024) inclusive scan -> row_ptr[g+1], chunk totals -> partials[b]
__global__ __launch_bounds__(1024) void k_scanA(const int* __restrict__ cnt,
                                                int* __restrict__ row_ptr,
                                                int* __restrict__ partials) {
    __shared__ int s[1024];
    int t = threadIdx.x;
    int g = blockIdx.x * 1024 + t;
    int v = (g < NN) ? cnt[g] : 0;
    s[t] = v;
    __syncthreads();
    for (int off = 1; off < 1024; off <<= 1) {
        int add = (t >= off) ? s[t - off] : 0;
        __syncthreads();
        s[t] += add;
        __syncthreads();
    }
    if (g < NN) row_ptr[g + 1] = s[t];
    if (t == 1023) partials[blockIdx.x] = s[t];
}

__global__ void k_scanB(int* __restrict__ partials, int nb) {
    if (threadIdx.x == 0 && blockIdx.x == 0) {
        int run = 0;
        for (int i = 0; i < nb; i++) { int v = partials[i]; partials[i] = run; run += v; }
    }
}

__global__ void k_scanC(int* __restrict__ row_ptr, const int* __restrict__ partials) {
    int g = blockIdx.x * blockDim.x + threadIdx.x;
    if (g < NN) row_ptr[g + 1] += partials[g >> 10];
    if (g == 0) row_ptr[0] = 0;
}

__global__ void k_dis(const int* __restrict__ row_ptr, float* __restrict__ dis) {
    int n = blockIdx.x * blockDim.x + threadIdx.x;
    if (n < NN) {
        int deg = row_ptr[n + 1] - row_ptr[n];
        dis[n] = rsqrtf((float)deg + 1.0f);  // +1 self-loop
    }
}

// scatter edges into CSR slots; record {src, dis[src]*dis[dst]} as float2
__global__ void k_fill(const int* __restrict__ src, const int* __restrict__ dst,
                       const int* __restrict__ row_ptr, const float* __restrict__ dis,
                       int* __restrict__ fill, float2* __restrict__ cw) {
    int i = blockIdx.x * blockDim.x + threadIdx.x;
    if (i < NE) {
        int s = src[i], d = dst[i];
        int slot = row_ptr[d] + atomicAdd(&fill[d], 1);
        cw[slot] = make_float2(__int_as_float(s), dis[s] * dis[d]);
    }
}

// ---------------- initial matmul (x @ W -> xw, copy x -> x_cur) ----------------

__global__ __launch_bounds__(256) void k_matmul(const float* __restrict__ src,
                                                const float* __restrict__ W,
                                                float* __restrict__ xw,
                                                float* __restrict__ copy_out) {
    __shared__ float sW[DIM * DIM];
    __shared__ float sX[32 * 33];
    int t = threadIdx.x;
#pragma unroll
    for (int k = 0; k < 4; k++) { int i = k * 256 + t; sW[i] = W[i]; }
    size_t base = (size_t)blockIdx.x * 32 * DIM;
#pragma unroll
    for (int k = 0; k < 4; k++) {
        int i = k * 256 + t;  // 0..1023, coalesced
        size_t g = base + i;
        float v = 0.f;
        if (g < (size_t)NN * DIM) {
            v = src[g];
            copy_out[g] = v;
        }
        sX[(i >> 5) * 33 + (i & 31)] = v;
    }
    __syncthreads();
    int r = t >> 3, oct = t & 7;
    int row = blockIdx.x * 32 + r;
    if (row >= NN) return;
    float a0 = 0.f, a1 = 0.f, a2 = 0.f, a3 = 0.f;
    const float* xr = &sX[r * 33];
#pragma unroll
    for (int i = 0; i < DIM; i++) {
        float xv = xr[i];
        const float* wr = &sW[i * DIM + oct * 4];
        a0 = fmaf(xv, wr[0], a0);
        a1 = fmaf(xv, wr[1], a1);
        a2 = fmaf(xv, wr[2], a2);
        a3 = fmaf(xv, wr[3], a3);
    }
    float4 o = make_float4(a0, a1, a2, a3);
    *(float4*)&xw[(size_t)row * DIM + oct * 4] = o;
}

// ---------------- fused stage kernel ----------------
// Per RK4 stage, both signs in one grid (blockIdx >= NBLK -> neg sign).
// Edge-aggregate from xw_in -> kv -> acc update -> next-stage input row r
//  mode 1: acc  = kv          ; r = x_cur + (h/2) kv
//  mode 2: acc += 2 kv        ; r = x_cur + (h/2) kv
//  mode 3: acc += 2 kv        ; r = x_cur +  h    kv
//  mode 4: a = acc + kv       ; r = x_cur + (h/6) a ; x_cur = r
//  mode 5: same as 4 but r -> zout, no matmul (final)
// Then (modes 1-4) epilogue matmul: xw_out = r @ W via LDS tile.

struct SignP {
    const int* row_ptr; const float2* cw; const float* dis;
    const float* xw_in; float* xw_out;
    float* acc; float* x_cur;
    const float* W; const float* b; const float* wt;
    float* zout;
};
struct StageArgs { SignP s[2]; float t, acc_coef, stage_coef; int mode; };

__global__ __launch_bounds__(256) void k_stage(StageArgs A) {
    int blk = blockIdx.x;
    int sg = 0;
    if (blk >= NBLK) { sg = 1; blk -= NBLK; }
    SignP P = A.s[sg];

    __shared__ float sW[DIM * DIM];   // 4 KB
    __shared__ float sR[32 * 36];     // 4.5 KB, stride 36: 16B-aligned rows, conflict-free
    int tid = threadIdx.x;
    if (A.mode != 5) {
#pragma unroll
        for (int k = 0; k < 4; k++) { int i = k * 256 + tid; sW[i] = P.W[i]; }
    }

    int q = tid & 7;              // column quad
    int nl = tid >> 3;            // local node 0..31
    int n = blk * 32 + nl;
    bool active = n < NN;
    float4 r4 = make_float4(0.f, 0.f, 0.f, 0.f);

    if (active) {
        int e0 = P.row_ptr[n], e1 = P.row_ptr[n + 1];
        const float* xwq = P.xw_in + q * 4;
        float4 sum = make_float4(0.f, 0.f, 0.f, 0.f);
        int e = e0;
        for (; e + 3 < e1; e += 4) {
            float2 p0 = P.cw[e];
            float2 p1 = P.cw[e + 1];
            float2 p2 = P.cw[e + 2];
            float2 p3 = P.cw[e + 3];
            float4 v0 = *(const float4*)&xwq[(size_t)__float_as_int(p0.x) * DIM];
            float4 v1 = *(const float4*)&xwq[(size_t)__float_as_int(p1.x) * DIM];
            float4 v2 = *(const float4*)&xwq[(size_t)__float_as_int(p2.x) * DIM];
            float4 v3 = *(const float4*)&xwq[(size_t)__float_as_int(p3.x) * DIM];
            sum.x = fmaf(p0.y, v0.x, sum.x); sum.y = fmaf(p0.y, v0.y, sum.y);
            sum.z = fmaf(p0.y, v0.z, sum.z); sum.w = fmaf(p0.y, v0.w, sum.w);
            sum.x = fmaf(p1.y, v1.x, sum.x); sum.y = fmaf(p1.y, v1.y, sum.y);
            sum.z = fmaf(p1.y, v1.z, sum.z); sum.w = fmaf(p1.y, v1.w, sum.w);
            sum.x = fmaf(p2.y, v2.x, sum.x); sum.y = fmaf(p2.y, v2.y, sum.y);
            sum.z = fmaf(p2.y, v2.z, sum.z); sum.w = fmaf(p2.y, v2.w, sum.w);
            sum.x = fmaf(p3.y, v3.x, sum.x); sum.y = fmaf(p3.y, v3.y, sum.y);
            sum.z = fmaf(p3.y, v3.z, sum.z); sum.w = fmaf(p3.y, v3.w, sum.w);
        }
        for (; e < e1; ++e) {
            float2 p = P.cw[e];
            float4 v = *(const float4*)&xwq[(size_t)__float_as_int(p.x) * DIM];
            sum.x = fmaf(p.y, v.x, sum.x); sum.y = fmaf(p.y, v.y, sum.y);
            sum.z = fmaf(p.y, v.z, sum.z); sum.w = fmaf(p.y, v.w, sum.w);
        }
        float dn = P.dis[n];
        float sn = dn * dn;
        float4 vn = *(const float4*)&xwq[(size_t)n * DIM];
        float4 bb = *(const float4*)&P.b[q * 4];
        sum.x = fmaf(sn, vn.x, sum.x) + bb.x;
        sum.y = fmaf(sn, vn.y, sum.y) + bb.y;
        sum.z = fmaf(sn, vn.z, sum.z) + bb.z;
        sum.w = fmaf(sn, vn.w, sum.w) + bb.w;
        float4 w4 = *(const float4*)&P.wt[q * 4];
        float t = A.t;
        float4 kv;
        kv.x = fmaxf(sum.x, 0.f) / (1.f + __expf(-t * w4.x));
        kv.y = fmaxf(sum.y, 0.f) / (1.f + __expf(-t * w4.y));
        kv.z = fmaxf(sum.z, 0.f) / (1.f + __expf(-t * w4.z));
        kv.w = fmaxf(sum.w, 0.f) / (1.f + __expf(-t * w4.w));

        size_t o = (size_t)n * DIM + q * 4;
        float4 xc = *(const float4*)&P.x_cur[o];
        if (A.mode == 1) {
            *(float4*)&P.acc[o] = kv;
            r4.x = fmaf(A.stage_coef, kv.x, xc.x); r4.y = fmaf(A.stage_coef, kv.y, xc.y);
            r4.z = fmaf(A.stage_coef, kv.z, xc.z); r4.w = fmaf(A.stage_coef, kv.w, xc.w);
        } else if (A.mode <= 3) {
            float4 ap = *(const float4*)&P.acc[o];
            float4 a;
            a.x = fmaf(A.acc_coef, kv.x, ap.x); a.y = fmaf(A.acc_coef, kv.y, ap.y);
            a.z = fmaf(A.acc_coef, kv.z, ap.z); a.w = fmaf(A.acc_coef, kv.w, ap.w);
            *(float4*)&P.acc[o] = a;
            r4.x = fmaf(A.stage_coef, kv.x, xc.x); r4.y = fmaf(A.stage_coef, kv.y, xc.y);
            r4.z = fmaf(A.stage_coef, kv.z, xc.z); r4.w = fmaf(A.stage_coef, kv.w, xc.w);
        } else {
            float4 ap = *(const float4*)&P.acc[o];
            float4 a;
            a.x = ap.x + kv.x; a.y = ap.y + kv.y;
            a.z = ap.z + kv.z; a.w = ap.w + kv.w;
            r4.x = fmaf(HS / 6.f, a.x, xc.x); r4.y = fmaf(HS / 6.f, a.y, xc.y);
            r4.z = fmaf(HS / 6.f, a.z, xc.z); r4.w = fmaf(HS / 6.f, a.w, xc.w);
            if (A.mode == 4) {
                *(float4*)&P.x_cur[o] = r4;
            } else {
                *(float4*)&P.zout[o] = r4;
            }
        }
    }

    if (A.mode == 5) return;  // uniform across grid; no one reaches the barrier

    // epilogue matmul: xw_out[n] = r4-row @ W
    *(float4*)&sR[nl * 36 + q * 4] = r4;
    __syncthreads();
    if (active) {
        float4 y = make_float4(0.f, 0.f, 0.f, 0.f);
        const float* row = &sR[nl * 36];
#pragma unroll
        for (int i = 0; i < DIM; i++) {
            float sv = row[i];
            float4 w = *(const float4*)&sW[i * DIM + q * 4];
            y.x = fmaf(sv, w.x, y.x); y.y = fmaf(sv, w.y, y.y);
            y.z = fmaf(sv, w.z, y.z); y.w = fmaf(sv, w.w, y.w);
        }
        *(float4*)&P.xw_out[(size_t)n * DIM + q * 4] = y;
    }
}

// ---------------- host ----------------

extern "C" void kernel_launch(void* const* d_in, const int* in_sizes, int n_in,
                              void* d_out, int out_size, void* d_ws, size_t ws_size,
                              hipStream_t stream) {
    const float* x   = (const float*)d_in[0];
    const int* epos  = (const int*)d_in[1];
    const int* eneg  = (const int*)d_in[2];
    const float* Wp  = (const float*)d_in[3];
    const float* bp  = (const float*)d_in[4];
    const float* wtp = (const float*)d_in[5];
    const float* Wn  = (const float*)d_in[6];
    const float* bn  = (const float*)d_in[7];
    const float* wtn = (const float*)d_in[8];
    float* out = (float*)d_out;

    char* ws = (char*)d_ws;
    size_t off = 0;
    auto alloc = [&](size_t bytes) -> void* {
        void* p = ws + off;
        off += (bytes + 255) & ~(size_t)255;
        return p;
    };

    struct Sign {
        int *row_ptr, *cnt, *fill, *partials;
        float* dis;
        float2* cw;
        float *x_cur, *acc;
        float* xwbuf[2];
        const int *src, *dst;
        const float *W, *b, *wt;
        float* zout;
    } S[2];

    for (int s = 0; s < 2; s++) {
        S[s].row_ptr  = (int*)alloc((NN + 1) * sizeof(int));
        int* cntfill  = (int*)alloc((size_t)2 * NN * sizeof(int));
        S[s].cnt = cntfill;
        S[s].fill = cntfill + NN;
        S[s].partials = (int*)alloc(256);
        S[s].dis      = (float*)alloc(NN * sizeof(float));
        S[s].cw       = (float2*)alloc((size_t)NE * sizeof(float2));
        S[s].x_cur    = (float*)alloc((size_t)NN * DIM * sizeof(float));
        S[s].acc      = (float*)alloc((size_t)NN * DIM * sizeof(float));
        S[s].xwbuf[0] = (float*)alloc((size_t)NN * DIM * sizeof(float));
        S[s].xwbuf[1] = (float*)alloc((size_t)NN * DIM * sizeof(float));
    }
    S[0].src = epos; S[0].dst = epos + NE; S[0].W = Wp; S[0].b = bp; S[0].wt = wtp;
    S[0].zout = out;
    S[1].src = eneg; S[1].dst = eneg + NE; S[1].W = Wn; S[1].b = bn; S[1].wt = wtn;
    S[1].zout = out + (size_t)NN * DIM;

    const int nbScan = cdiv(NN, 1024);

    // ---- setup: build CSR + norms for both signs ----
    for (int s = 0; s < 2; s++) {
        k_zero_ints<<<cdiv(2 * NN, 256), 256, 0, stream>>>(S[s].cnt, 2 * NN);
        k_hist<<<cdiv(NE, 256), 256, 0, stream>>>(S[s].dst, S[s].cnt);
        k_scanA<<<nbScan, 1024, 0, stream>>>(S[s].cnt, S[s].row_ptr, S[s].partials);
        k_scanB<<<1, 1, 0, stream>>>(S[s].partials, nbScan);
        k_scanC<<<cdiv(NN, 256), 256, 0, stream>>>(S[s].row_ptr, S[s].partials);
        k_dis<<<cdiv(NN, 256), 256, 0, stream>>>(S[s].row_ptr, S[s].dis);
        k_fill<<<cdiv(NE, 256), 256, 0, stream>>>(S[s].src, S[s].dst, S[s].row_ptr,
                                                  S[s].dis, S[s].fill, S[s].cw);
    }

    // initial xw = x @ W, x_cur = x
    for (int s = 0; s < 2; s++)
        k_matmul<<<NBLK, 256, 0, stream>>>(x, S[s].W, S[s].xwbuf[0], S[s].x_cur);

    // ---- RK4 main loop: 4 fused stages per step, both signs per dispatch ----
    for (int st = 0; st < 10; st++) {
        float tb = HS * (float)st;
        struct Ph { float t, ac, sc; int mode, in, out; } ph[4] = {
            { tb,             1.f, HS * 0.5f, 1,              0, 1 },
            { tb + HS * 0.5f, 2.f, HS * 0.5f, 2,              1, 0 },
            { tb + HS * 0.5f, 2.f, HS,        3,              0, 1 },
            { tb + HS,        1.f, 0.f,       st == 9 ? 5 : 4, 1, 0 },
        };
        for (int p = 0; p < 4; p++) {
            StageArgs A;
            for (int s = 0; s < 2; s++) {
                A.s[s].row_ptr = S[s].row_ptr;
                A.s[s].cw      = S[s].cw;
                A.s[s].dis     = S[s].dis;
                A.s[s].xw_in   = S[s].xwbuf[ph[p].in];
                A.s[s].xw_out  = S[s].xwbuf[ph[p].out];
                A.s[s].acc     = S[s].acc;
                A.s[s].x_cur   = S[s].x_cur;
                A.s[s].W       = S[s].W;
                A.s[s].b       = S[s].b;
                A.s[s].wt      = S[s].wt;
                A.s[s].zout    = S[s].zout;
            }
            A.t = ph[p].t; A.acc_coef = ph[p].ac; A.stage_coef = ph[p].sc;
            A.mode = ph[p].mode;
            k_stage<<<2 * NBLK, 256, 0, stream>>>(A);
        }
    }
}

// Round 4
// 2094.519 us; speedup vs baseline: 3.8303x; 1.2105x over previous
//
#include <hip/hip_runtime.h>

#define NN 50000
#define NE 1600000
#define DIM 32
#define HS 0.1f
#define NBLK 1563   // cdiv(NN, 32)

static inline int cdiv(int a, int b) { return (a + b - 1) / b; }

// bf16x2 (packed in uint) -> 2 floats; bf16x4 (uint2) -> float4
__device__ __forceinline__ float4 bf4_to_f4(uint2 u) {
    float4 v;
    v.x = __uint_as_float(u.x << 16);
    v.y = __uint_as_float(u.x & 0xffff0000u);
    v.z = __uint_as_float(u.y << 16);
    v.w = __uint_as_float(u.y & 0xffff0000u);
    return v;
}
// pack 2 floats -> bf16x2 with round-to-nearest-even
__device__ __forceinline__ unsigned pack_bf2(float a, float b) {
    unsigned ua = __float_as_uint(a);
    ua = (ua + 0x7fffu + ((ua >> 16) & 1u)) >> 16;
    unsigned ub = __float_as_uint(b);
    ub = (ub + 0x7fffu + ((ub >> 16) & 1u)) & 0xffff0000u;
    return ua | ub;
}

// ---------------- setup kernels ----------------

__global__ void k_zero_ints(int* __restrict__ p, int n) {
    int i = blockIdx.x * blockDim.x + threadIdx.x;
    if (i < n) p[i] = 0;
}

__global__ void k_hist(const int* __restrict__ dst, int* __restrict__ cnt) {
    int i = blockIdx.x * blockDim.x + threadIdx.x;
    if (i < NE) atomicAdd(&cnt[dst[i]], 1);
}

// per-chunk (1024) inclusive scan -> row_ptr[g+1], chunk totals -> partials[b]
__global__ __launch_bounds__(1024) void k_scanA(const int* __restrict__ cnt,
                                                int* __restrict__ row_ptr,
                                                int* __restrict__ partials) {
    __shared__ int s[1024];
    int t = threadIdx.x;
    int g = blockIdx.x * 1024 + t;
    int v = (g < NN) ? cnt[g] : 0;
    s[t] = v;
    __syncthreads();
    for (int off = 1; off < 1024; off <<= 1) {
        int add = (t >= off) ? s[t - off] : 0;
        __syncthreads();
        s[t] += add;
        __syncthreads();
    }
    if (g < NN) row_ptr[g + 1] = s[t];
    if (t == 1023) partials[blockIdx.x] = s[t];
}

__global__ void k_scanB(int* __restrict__ partials, int nb) {
    if (threadIdx.x == 0 && blockIdx.x == 0) {
        int run = 0;
        for (int i = 0; i < nb; i++) { int v = partials[i]; partials[i] = run; run += v; }
    }
}

__global__ void k_scanC(int* __restrict__ row_ptr, const int* __restrict__ partials) {
    int g = blockIdx.x * blockDim.x + threadIdx.x;
    if (g < NN) row_ptr[g + 1] += partials[g >> 10];
    if (g == 0) row_ptr[0] = 0;
}

__global__ void k_dis(const int* __restrict__ row_ptr, float* __restrict__ dis) {
    int n = blockIdx.x * blockDim.x + threadIdx.x;
    if (n < NN) {
        int deg = row_ptr[n + 1] - row_ptr[n];
        dis[n] = rsqrtf((float)deg + 1.0f);  // +1 self-loop
    }
}

// scatter edges into CSR slots; record {src, dis[src]*dis[dst]} as float2
__global__ void k_fill(const int* __restrict__ src, const int* __restrict__ dst,
                       const int* __restrict__ row_ptr, const float* __restrict__ dis,
                       int* __restrict__ fill, float2* __restrict__ cw) {
    int i = blockIdx.x * blockDim.x + threadIdx.x;
    if (i < NE) {
        int s = src[i], d = dst[i];
        int slot = row_ptr[d] + atomicAdd(&fill[d], 1);
        cw[slot] = make_float2(__int_as_float(s), dis[s] * dis[d]);
    }
}

// ---------------- initial matmul (x @ W -> xw bf16, copy x -> x_cur) ----------------

__global__ __launch_bounds__(256) void k_matmul(const float* __restrict__ src,
                                                const float* __restrict__ W,
                                                uint2* __restrict__ xw,
                                                float* __restrict__ copy_out) {
    __shared__ float sW[DIM * DIM];
    __shared__ float sX[32 * 33];
    int t = threadIdx.x;
#pragma unroll
    for (int k = 0; k < 4; k++) { int i = k * 256 + t; sW[i] = W[i]; }
    size_t base = (size_t)blockIdx.x * 32 * DIM;
#pragma unroll
    for (int k = 0; k < 4; k++) {
        int i = k * 256 + t;  // 0..1023, coalesced
        size_t g = base + i;
        float v = 0.f;
        if (g < (size_t)NN * DIM) {
            v = src[g];
            copy_out[g] = v;
        }
        sX[(i >> 5) * 33 + (i & 31)] = v;
    }
    __syncthreads();
    int r = t >> 3, oct = t & 7;
    int row = blockIdx.x * 32 + r;
    if (row >= NN) return;
    float a0 = 0.f, a1 = 0.f, a2 = 0.f, a3 = 0.f;
    const float* xr = &sX[r * 33];
#pragma unroll
    for (int i = 0; i < DIM; i++) {
        float xv = xr[i];
        const float* wr = &sW[i * DIM + oct * 4];
        a0 = fmaf(xv, wr[0], a0);
        a1 = fmaf(xv, wr[1], a1);
        a2 = fmaf(xv, wr[2], a2);
        a3 = fmaf(xv, wr[3], a3);
    }
    xw[(size_t)row * 8 + oct] = make_uint2(pack_bf2(a0, a1), pack_bf2(a2, a3));
}

// ---------------- fused stage kernel ----------------
// Per RK4 stage, both signs in one grid (blockIdx >= NBLK -> neg sign).
// xw held in bf16 (row = 64 B, L2-resident: 3.2 MB per sign).
//  mode 1: acc  = kv          ; r = x_cur + (h/2) kv
//  mode 2: acc += 2 kv        ; r = x_cur + (h/2) kv
//  mode 3: acc += 2 kv        ; r = x_cur +  h    kv
//  mode 4: a = acc + kv       ; r = x_cur + (h/6) a ; x_cur = r
//  mode 5: same as 4 but r -> zout, no matmul (final)
// Then (modes 1-4) epilogue matmul: xw_out = r @ W via LDS tile, bf16 store.

struct SignP {
    const int* row_ptr; const float2* cw; const float* dis;
    const uint2* xw_in; uint2* xw_out;
    float* acc; float* x_cur;
    const float* W; const float* b; const float* wt;
    float* zout;
};
struct StageArgs { SignP s[2]; float t, acc_coef, stage_coef; int mode; };

#define EDGE_FMA(p, u)                                              \
    {                                                               \
        float4 v = bf4_to_f4(u);                                    \
        sum.x = fmaf((p).y, v.x, sum.x);                            \
        sum.y = fmaf((p).y, v.y, sum.y);                            \
        sum.z = fmaf((p).y, v.z, sum.z);                            \
        sum.w = fmaf((p).y, v.w, sum.w);                            \
    }

__global__ __launch_bounds__(256) void k_stage(StageArgs A) {
    int blk = blockIdx.x;
    int sg = 0;
    if (blk >= NBLK) { sg = 1; blk -= NBLK; }
    SignP P = A.s[sg];

    __shared__ float sW[DIM * DIM];   // 4 KB
    __shared__ float sR[32 * 36];     // 4.5 KB, stride 36: 16B-aligned rows, conflict-free
    int tid = threadIdx.x;
    if (A.mode != 5) {
#pragma unroll
        for (int k = 0; k < 4; k++) { int i = k * 256 + tid; sW[i] = P.W[i]; }
    }

    int q = tid & 7;              // column quad (4 cols = 8 B bf16)
    int nl = tid >> 3;            // local node 0..31
    int n = blk * 32 + nl;
    bool active = n < NN;
    float4 r4 = make_float4(0.f, 0.f, 0.f, 0.f);

    if (active) {
        int e0 = P.row_ptr[n], e1 = P.row_ptr[n + 1];
        const uint2* xwq = P.xw_in + q;   // row stride = 8 uint2 (64 B)
        float4 sum = make_float4(0.f, 0.f, 0.f, 0.f);
        int e = e0;
        // unroll 8: 8 independent cw loads + 8 independent 8B gathers in flight
        for (; e + 7 < e1; e += 8) {
            float2 p0 = P.cw[e];
            float2 p1 = P.cw[e + 1];
            float2 p2 = P.cw[e + 2];
            float2 p3 = P.cw[e + 3];
            float2 p4 = P.cw[e + 4];
            float2 p5 = P.cw[e + 5];
            float2 p6 = P.cw[e + 6];
            float2 p7 = P.cw[e + 7];
            uint2 u0 = xwq[(size_t)__float_as_int(p0.x) * 8];
            uint2 u1 = xwq[(size_t)__float_as_int(p1.x) * 8];
            uint2 u2 = xwq[(size_t)__float_as_int(p2.x) * 8];
            uint2 u3 = xwq[(size_t)__float_as_int(p3.x) * 8];
            uint2 u4 = xwq[(size_t)__float_as_int(p4.x) * 8];
            uint2 u5 = xwq[(size_t)__float_as_int(p5.x) * 8];
            uint2 u6 = xwq[(size_t)__float_as_int(p6.x) * 8];
            uint2 u7 = xwq[(size_t)__float_as_int(p7.x) * 8];
            EDGE_FMA(p0, u0) EDGE_FMA(p1, u1) EDGE_FMA(p2, u2) EDGE_FMA(p3, u3)
            EDGE_FMA(p4, u4) EDGE_FMA(p5, u5) EDGE_FMA(p6, u6) EDGE_FMA(p7, u7)
        }
        for (; e < e1; ++e) {
            float2 p = P.cw[e];
            uint2 u = xwq[(size_t)__float_as_int(p.x) * 8];
            EDGE_FMA(p, u)
        }
        float dn = P.dis[n];
        float sn = dn * dn;
        float4 vn = bf4_to_f4(xwq[(size_t)n * 8]);
        float4 bb = *(const float4*)&P.b[q * 4];
        sum.x = fmaf(sn, vn.x, sum.x) + bb.x;
        sum.y = fmaf(sn, vn.y, sum.y) + bb.y;
        sum.z = fmaf(sn, vn.z, sum.z) + bb.z;
        sum.w = fmaf(sn, vn.w, sum.w) + bb.w;
        float4 w4 = *(const float4*)&P.wt[q * 4];
        float t = A.t;
        float4 kv;
        kv.x = fmaxf(sum.x, 0.f) / (1.f + __expf(-t * w4.x));
        kv.y = fmaxf(sum.y, 0.f) / (1.f + __expf(-t * w4.y));
        kv.z = fmaxf(sum.z, 0.f) / (1.f + __expf(-t * w4.z));
        kv.w = fmaxf(sum.w, 0.f) / (1.f + __expf(-t * w4.w));

        size_t o = (size_t)n * DIM + q * 4;
        float4 xc = *(const float4*)&P.x_cur[o];
        if (A.mode == 1) {
            *(float4*)&P.acc[o] = kv;
            r4.x = fmaf(A.stage_coef, kv.x, xc.x); r4.y = fmaf(A.stage_coef, kv.y, xc.y);
            r4.z = fmaf(A.stage_coef, kv.z, xc.z); r4.w = fmaf(A.stage_coef, kv.w, xc.w);
        } else if (A.mode <= 3) {
            float4 ap = *(const float4*)&P.acc[o];
            float4 a;
            a.x = fmaf(A.acc_coef, kv.x, ap.x); a.y = fmaf(A.acc_coef, kv.y, ap.y);
            a.z = fmaf(A.acc_coef, kv.z, ap.z); a.w = fmaf(A.acc_coef, kv.w, ap.w);
            *(float4*)&P.acc[o] = a;
            r4.x = fmaf(A.stage_coef, kv.x, xc.x); r4.y = fmaf(A.stage_coef, kv.y, xc.y);
            r4.z = fmaf(A.stage_coef, kv.z, xc.z); r4.w = fmaf(A.stage_coef, kv.w, xc.w);
        } else {
            float4 ap = *(const float4*)&P.acc[o];
            float4 a;
            a.x = ap.x + kv.x; a.y = ap.y + kv.y;
            a.z = ap.z + kv.z; a.w = ap.w + kv.w;
            r4.x = fmaf(HS / 6.f, a.x, xc.x); r4.y = fmaf(HS / 6.f, a.y, xc.y);
            r4.z = fmaf(HS / 6.f, a.z, xc.z); r4.w = fmaf(HS / 6.f, a.w, xc.w);
            if (A.mode == 4) {
                *(float4*)&P.x_cur[o] = r4;
            } else {
                *(float4*)&P.zout[o] = r4;
            }
        }
    }

    if (A.mode == 5) return;  // uniform across grid; no one reaches the barrier

    // epilogue matmul: xw_out[n] = r4-row @ W, stored bf16
    *(float4*)&sR[nl * 36 + q * 4] = r4;
    __syncthreads();
    if (active) {
        float4 y = make_float4(0.f, 0.f, 0.f, 0.f);
        const float* row = &sR[nl * 36];
#pragma unroll
        for (int i = 0; i < DIM; i++) {
            float sv = row[i];
            float4 w = *(const float4*)&sW[i * DIM + q * 4];
            y.x = fmaf(sv, w.x, y.x); y.y = fmaf(sv, w.y, y.y);
            y.z = fmaf(sv, w.z, y.z); y.w = fmaf(sv, w.w, y.w);
        }
        P.xw_out[(size_t)n * 8 + q] = make_uint2(pack_bf2(y.x, y.y), pack_bf2(y.z, y.w));
    }
}

// ---------------- host ----------------

extern "C" void kernel_launch(void* const* d_in, const int* in_sizes, int n_in,
                              void* d_out, int out_size, void* d_ws, size_t ws_size,
                              hipStream_t stream) {
    const float* x   = (const float*)d_in[0];
    const int* epos  = (const int*)d_in[1];
    const int* eneg  = (const int*)d_in[2];
    const float* Wp  = (const float*)d_in[3];
    const float* bp  = (const float*)d_in[4];
    const float* wtp = (const float*)d_in[5];
    const float* Wn  = (const float*)d_in[6];
    const float* bn  = (const float*)d_in[7];
    const float* wtn = (const float*)d_in[8];
    float* out = (float*)d_out;

    char* ws = (char*)d_ws;
    size_t off = 0;
    auto alloc = [&](size_t bytes) -> void* {
        void* p = ws + off;
        off += (bytes + 255) & ~(size_t)255;
        return p;
    };

    struct Sign {
        int *row_ptr, *cnt, *fill, *partials;
        float* dis;
        float2* cw;
        float *x_cur, *acc;
        uint2* xwbuf[2];
        const int *src, *dst;
        const float *W, *b, *wt;
        float* zout;
    } S[2];

    for (int s = 0; s < 2; s++) {
        S[s].row_ptr  = (int*)alloc((NN + 1) * sizeof(int));
        int* cntfill  = (int*)alloc((size_t)2 * NN * sizeof(int));
        S[s].cnt = cntfill;
        S[s].fill = cntfill + NN;
        S[s].partials = (int*)alloc(256);
        S[s].dis      = (float*)alloc(NN * sizeof(float));
        S[s].cw       = (float2*)alloc((size_t)NE * sizeof(float2));
        S[s].x_cur    = (float*)alloc((size_t)NN * DIM * sizeof(float));
        S[s].acc      = (float*)alloc((size_t)NN * DIM * sizeof(float));
        S[s].xwbuf[0] = (uint2*)alloc((size_t)NN * DIM * 2);
        S[s].xwbuf[1] = (uint2*)alloc((size_t)NN * DIM * 2);
    }
    S[0].src = epos; S[0].dst = epos + NE; S[0].W = Wp; S[0].b = bp; S[0].wt = wtp;
    S[0].zout = out;
    S[1].src = eneg; S[1].dst = eneg + NE; S[1].W = Wn; S[1].b = bn; S[1].wt = wtn;
    S[1].zout = out + (size_t)NN * DIM;

    const int nbScan = cdiv(NN, 1024);

    // ---- setup: build CSR + norms for both signs ----
    for (int s = 0; s < 2; s++) {
        k_zero_ints<<<cdiv(2 * NN, 256), 256, 0, stream>>>(S[s].cnt, 2 * NN);
        k_hist<<<cdiv(NE, 256), 256, 0, stream>>>(S[s].dst, S[s].cnt);
        k_scanA<<<nbScan, 1024, 0, stream>>>(S[s].cnt, S[s].row_ptr, S[s].partials);
        k_scanB<<<1, 1, 0, stream>>>(S[s].partials, nbScan);
        k_scanC<<<cdiv(NN, 256), 256, 0, stream>>>(S[s].row_ptr, S[s].partials);
        k_dis<<<cdiv(NN, 256), 256, 0, stream>>>(S[s].row_ptr, S[s].dis);
        k_fill<<<cdiv(NE, 256), 256, 0, stream>>>(S[s].src, S[s].dst, S[s].row_ptr,
                                                  S[s].dis, S[s].fill, S[s].cw);
    }

    // initial xw = bf16(x @ W), x_cur = x
    for (int s = 0; s < 2; s++)
        k_matmul<<<NBLK, 256, 0, stream>>>(x, S[s].W, S[s].xwbuf[0], S[s].x_cur);

    // ---- RK4 main loop: 4 fused stages per step, both signs per dispatch ----
    for (int st = 0; st < 10; st++) {
        float tb = HS * (float)st;
        struct Ph { float t, ac, sc; int mode, in, out; } ph[4] = {
            { tb,             1.f, HS * 0.5f, 1,              0, 1 },
            { tb + HS * 0.5f, 2.f, HS * 0.5f, 2,              1, 0 },
            { tb + HS * 0.5f, 2.f, HS,        3,              0, 1 },
            { tb + HS,        1.f, 0.f,       st == 9 ? 5 : 4, 1, 0 },
        };
        for (int p = 0; p < 4; p++) {
            StageArgs A;
            for (int s = 0; s < 2; s++) {
                A.s[s].row_ptr = S[s].row_ptr;
                A.s[s].cw      = S[s].cw;
                A.s[s].dis     = S[s].dis;
                A.s[s].xw_in   = S[s].xwbuf[ph[p].in];
                A.s[s].xw_out  = S[s].xwbuf[ph[p].out];
                A.s[s].acc     = S[s].acc;
                A.s[s].x_cur   = S[s].x_cur;
                A.s[s].W       = S[s].W;
                A.s[s].b       = S[s].b;
                A.s[s].wt      = S[s].wt;
                A.s[s].zout    = S[s].zout;
            }
            A.t = ph[p].t; A.acc_coef = ph[p].ac; A.stage_coef = ph[p].sc;
            A.mode = ph[p].mode;
            k_stage<<<2 * NBLK, 256, 0, stream>>>(A);
        }
    }
}